// Round 1
// baseline (204.418 us; speedup 1.0000x reference)
//
#include <hip/hip_runtime.h>

// YOLOv1 loss: pred/label (16384, 30, 7, 7) fp32 -> scalar.
// One thread per cell; memory-bound streaming kernel.

#define NBATCH 16384
#define NCH 30
#define NCELL 49      // 7*7
#define BSTRIDE 1470  // 30*49
#define BLOCK 256

__device__ __forceinline__ float sq(float x) { return x * x; }

__device__ __forceinline__ float iou_vs_label(float x, float y, float w, float h,
                                              float fc, float fr,
                                              float lx1, float ly1, float lx2, float ly2,
                                              float larea) {
    const float inv7 = 1.0f / 7.0f;
    float cx = (x + fc) * inv7;
    float cy = (y + fr) * inv7;
    float hw = w * 0.5f, hh = h * 0.5f;
    float x1 = cx - hw, y1 = cy - hh;
    float x2 = cx + hw, y2 = cy + hh;
    float iw = fmaxf(fminf(x2, lx2) - fmaxf(x1, lx1), 0.0f);
    float ih = fmaxf(fminf(y2, ly2) - fmaxf(y1, ly1), 0.0f);
    float inter = iw * ih;
    float area = (x2 - x1) * (y2 - y1);
    return inter / (area + larea - inter + 1e-10f);
}

__global__ __launch_bounds__(BLOCK) void yolo_loss_kernel(const float* __restrict__ pred,
                                                          const float* __restrict__ label,
                                                          float* __restrict__ out) {
    const int tid = blockIdx.x * BLOCK + threadIdx.x;
    const int b = tid / NCELL;
    const int rc = tid - b * NCELL;
    const int r = rc / 7;
    const int c = rc - r * 7;

    const float* pb = pred + (size_t)b * BSTRIDE + rc;
    const float* lb = label + (size_t)b * BSTRIDE + rc;

    // Load all 30 pred channels; skip label channel 9 (never used by reference).
    float p[NCH];
#pragma unroll
    for (int ch = 0; ch < NCH; ++ch) p[ch] = pb[ch * NCELL];

    float l[NCH];
#pragma unroll
    for (int ch = 0; ch < NCH; ++ch) l[ch] = (ch == 9) ? 0.0f : lb[ch * NCELL];

    const float fc = (float)c, fr = (float)r;
    const float inv7 = 1.0f / 7.0f;

    // Label box (offset 0)
    float lcx = (l[0] + fc) * inv7;
    float lcy = (l[1] + fr) * inv7;
    float lhw = l[2] * 0.5f, lhh = l[3] * 0.5f;
    float lx1 = lcx - lhw, ly1 = lcy - lhh;
    float lx2 = lcx + lhw, ly2 = lcy + lhh;
    float larea = (lx2 - lx1) * (ly2 - ly1);

    float iou1 = iou_vs_label(p[0], p[1], p[2], p[3], fc, fr, lx1, ly1, lx2, ly2, larea);
    float iou2 = iou_vs_label(p[5], p[6], p[7], p[8], fc, fr, lx1, ly1, lx2, ly2, larea);
    bool choose1 = iou1 >= iou2;

    float coord1 = 5.0f * (sq(p[0] - l[0]) + sq(p[1] - l[1]))
                 + sq(sqrtf(p[2]) - sqrtf(l[2])) + sq(sqrtf(p[3]) - sqrtf(l[3]));
    float coord2 = 5.0f * (sq(p[5] - l[5]) + sq(p[6] - l[6]))
                 + sq(sqrtf(p[7]) - sqrtf(l[7])) + sq(sqrtf(p[8]) - sqrtf(l[8]));

    float obj1 = sq(p[4] - iou1);
    float obj2 = sq(p[9] - iou2);

    float coord      = choose1 ? coord1 : coord2;
    float obj_conf   = choose1 ? obj1 : obj2;
    float noobj_conf = 0.5f * (choose1 ? obj2 : obj1);

    float class_l = 0.0f;
#pragma unroll
    for (int ch = 10; ch < NCH; ++ch) class_l += sq(p[ch] - l[ch]);

    float obj_cell = coord + obj_conf + noobj_conf + class_l;
    float psum = p[4] + p[9];
    float noobj_cell = 0.5f * psum * psum;

    float per_cell = (l[4] == 1.0f) ? obj_cell : noobj_cell;

    // Reduce: wave shuffle -> LDS -> one atomic per block.
    float v = per_cell;
#pragma unroll
    for (int off = 32; off > 0; off >>= 1) v += __shfl_down(v, off, 64);

    __shared__ float smem[BLOCK / 64];
    const int lane = threadIdx.x & 63;
    const int wave = threadIdx.x >> 6;
    if (lane == 0) smem[wave] = v;
    __syncthreads();
    if (threadIdx.x == 0) {
        float s = smem[0] + smem[1] + smem[2] + smem[3];
        atomicAdd(out, s * (1.0f / (float)NBATCH));
    }
}

extern "C" void kernel_launch(void* const* d_in, const int* in_sizes, int n_in,
                              void* d_out, int out_size, void* d_ws, size_t ws_size,
                              hipStream_t stream) {
    const float* pred  = (const float*)d_in[0];
    const float* label = (const float*)d_in[1];
    float* out = (float*)d_out;

    // d_out is poisoned 0xAA before every launch; zero it (graph-capture safe).
    hipMemsetAsync(out, 0, sizeof(float), stream);

    const int total_cells = NBATCH * NCELL;       // 802816
    const int grid = total_cells / BLOCK;         // 3136, exact
    yolo_loss_kernel<<<grid, BLOCK, 0, stream>>>(pred, label, out);
}